// Round 2
// baseline (225.422 us; speedup 1.0000x reference)
//
#include <hip/hip_runtime.h>
#include <hip/hip_bf16.h>

typedef unsigned short u16;

#define BB 2
#define SS 4096
#define DM 768
#define NH 12
#define OUTC 512
#define QSCALE 0.125f
#define NCHUNK 64   // s-chunks per batch in kernel B
#define CS 64       // s per chunk

__device__ __forceinline__ float bf2f(u16 u) {
  union { unsigned int i; float f; } v; v.i = ((unsigned int)u) << 16; return v.f;
}

// dtype-polymorphic loaders: all inputs share one dtype, detected on device.
struct LDb {  // bf16
  __device__ static float s(const void* p, size_t i) { return bf2f(((const u16*)p)[i]); }
  __device__ static float4 v4(const void* p, size_t off, size_t q) {
    ushort4 u = ((const ushort4*)((const u16*)p + off))[q];
    return make_float4(bf2f(u.x), bf2f(u.y), bf2f(u.z), bf2f(u.w));
  }
  __device__ static void st(void* p, size_t i, float v) {
    ((__hip_bfloat16*)p)[i] = __float2bfloat16(v);
  }
};
struct LDf {  // fp32
  __device__ static float s(const void* p, size_t i) { return ((const float*)p)[i]; }
  __device__ static float4 v4(const void* p, size_t off, size_t q) {
    return ((const float4*)((const float*)p + off))[q];
  }
  __device__ static void st(void* p, size_t i, float v) { ((float*)p)[i] = v; }
};

__device__ __forceinline__ float wave_sum64(float v) {
#pragma unroll
  for (int o = 32; o > 0; o >>= 1) v += __shfl_xor(v, o, 64);
  return v;
}

// Prelude: classify input dtype. bf16 N(0,1) halfwords never have |v|>1e4;
// fp32 low halfwords (mantissa bits as exponent) do ~45% of the time.
__global__ __launch_bounds__(256) void kDetect(const u16* __restrict__ x, int* __restrict__ flag) {
  __shared__ int cnt;
  if (threadIdx.x == 0) cnt = 0;
  __syncthreads();
  float v = bf2f(x[threadIdx.x]);
  int bad = (!(fabsf(v) < 1e4f)) ? 1 : 0;  // also true for inf/nan encodings
  atomicAdd(&cnt, bad);
  __syncthreads();
  if (threadIdx.x == 0) flag[0] = (cnt > 8) ? 1 : 0;
}

// Kernel A: per (h,b): qg0 = (x[b,0,:]@wqg+bqg)[h*64:..]*scale; fold wkg into
// qw[b,h,:] and qb[b,h]. Also zero l and xw accumulators (ws is poisoned each call).
template<class LDT>
__device__ void kA_body(const void* x, const void* wqg, const void* bqg,
    const void* wkg, const void* bkg,
    float* qw_ws, float* qb_ws, float* l_ws, float* xw_ws) {
  int h = blockIdx.x, b = blockIdx.y, t = threadIdx.x;
  __shared__ float x0[DM];
  __shared__ float red[4][64];
  __shared__ float qg0[64];
  for (int i = t; i < DM; i += 256) {
    x0[i] = LDT::s(x, (size_t)b*SS*DM + i);
    xw_ws[((size_t)b*NH + h)*DM + i] = 0.f;
  }
  if (t == 0) l_ws[b*NH + h] = 0.f;
  __syncthreads();
  int d = t & 63, g = t >> 6;
  float p = 0.f;
  for (int j = g*192; j < g*192 + 192; ++j)
    p += x0[j] * LDT::s(wqg, (size_t)j*DM + h*64 + d);
  red[g][d] = p;
  __syncthreads();
  if (t < 64) {
    float s = red[0][t] + red[1][t] + red[2][t] + red[3][t] + LDT::s(bqg, h*64 + t);
    qg0[t] = s * QSCALE;
  }
  __syncthreads();
  if (t == 0) {
    float qb = 0.f;
    for (int dd = 0; dd < 64; ++dd) qb += qg0[dd] * LDT::s(bkg, h*64 + dd);
    qb_ws[b*NH + h] = qb;
  }
  for (int i = 0; i < 3; ++i) {
    int j = t + 256*i;
    float acc = 0.f;
    for (int dd = 0; dd < 64; ++dd) acc += qg0[dd] * LDT::s(wkg, (size_t)j*DM + h*64 + dd);
    qw_ws[((size_t)b*NH + h)*DM + j] = acc;
  }
}
__global__ __launch_bounds__(256) void kA(const void* x, const void* wqg, const void* bqg,
    const void* wkg, const void* bkg, float* qw, float* qb, float* l, float* xw,
    const int* flag) {
  if (*flag) kA_body<LDf>(x, wqg, bqg, wkg, bkg, qw, qb, l, xw);
  else       kA_body<LDb>(x, wqg, bqg, wkg, bkg, qw, qb, l, xw);
}

// Kernel B: fused scores + exp + l accumulation + weighted x row-sum (atomic).
template<class LDT>
__device__ void kB_body(const void* x, const float* qw_ws, const float* qb_ws,
    float* l_ws, float* xw_ws) {
  int chunk = blockIdx.x, b = blockIdx.y;
  int t = threadIdx.x, lane = t & 63, w = t >> 6;
  __shared__ alignas(16) float qw[NH*DM];   // 36 KB
  __shared__ float qb[NH];
  __shared__ alignas(16) float pl[CS*NH];   // 3 KB
  for (int i = t; i < NH*DM; i += 256) qw[i] = qw_ws[(size_t)b*NH*DM + i];
  if (t < NH) qb[t] = qb_ws[b*NH + t];
  __syncthreads();
  const size_t xbase = ((size_t)b*SS + chunk*CS) * DM;
  const float4* qw4 = (const float4*)qw;
  float lacc = 0.f;

  for (int batch = 0; batch < 4; ++batch) {
    int sl = w*16 + batch*4;
    float acc[4][NH];
#pragma unroll
    for (int si = 0; si < 4; ++si)
#pragma unroll
      for (int hh = 0; hh < NH; ++hh) acc[si][hh] = 0.f;
#pragma unroll
    for (int k = 0; k < 3; ++k) {
      int jq = k*64 + lane;            // float4-quad index in [0,192)
      float4 xf[4];
#pragma unroll
      for (int si = 0; si < 4; ++si)
        xf[si] = LDT::v4(x, xbase + (size_t)(sl + si)*DM, jq);
#pragma unroll
      for (int hh = 0; hh < NH; ++hh) {
        float4 qv = qw4[hh*192 + jq];
#pragma unroll
        for (int si = 0; si < 4; ++si)
          acc[si][hh] += xf[si].x*qv.x + xf[si].y*qv.y + xf[si].z*qv.z + xf[si].w*qv.w;
      }
    }
    float preg = 0.f;
#pragma unroll
    for (int si = 0; si < 4; ++si)
#pragma unroll
      for (int hh = 0; hh < NH; ++hh) {
        float r = wave_sum64(acc[si][hh]);
        float pp = __expf(r + qb[hh]);
        if (lane == hh) lacc += pp;
        if (lane == si*NH + hh) preg = pp;
      }
    if (lane < 4*NH) pl[(sl + lane/NH)*NH + (lane % NH)] = preg;
  }
  if (lane < NH) atomicAdd(&l_ws[b*NH + lane], lacc);
  __syncthreads();

  // phase 2: xw[b][h][:] += sum_s p[s,h] * x[s,:] over this chunk
  float a2[NH][3];
#pragma unroll
  for (int hh = 0; hh < NH; ++hh)
#pragma unroll
    for (int i = 0; i < 3; ++i) a2[hh][i] = 0.f;
  for (int s = 0; s < CS; ++s) {
    float4 p0 = *(const float4*)(&pl[s*NH + 0]);
    float4 p1 = *(const float4*)(&pl[s*NH + 4]);
    float4 p2 = *(const float4*)(&pl[s*NH + 8]);
    float pv[NH] = {p0.x,p0.y,p0.z,p0.w, p1.x,p1.y,p1.z,p1.w, p2.x,p2.y,p2.z,p2.w};
    float xv[3];
#pragma unroll
    for (int i = 0; i < 3; ++i)
      xv[i] = LDT::s(x, xbase + (size_t)s*DM + t + 256*i);
#pragma unroll
    for (int hh = 0; hh < NH; ++hh)
#pragma unroll
      for (int i = 0; i < 3; ++i) a2[hh][i] += pv[hh]*xv[i];
  }
#pragma unroll
  for (int hh = 0; hh < NH; ++hh)
#pragma unroll
    for (int i = 0; i < 3; ++i)
      atomicAdd(&xw_ws[((size_t)b*NH + hh)*DM + t + 256*i], a2[hh][i]);
}
__global__ __launch_bounds__(256) void kB(const void* x, const float* qw,
    const float* qb, float* l, float* xw, const int* flag) {
  if (*flag) kB_body<LDf>(x, qw, qb, l, xw);
  else       kB_body<LDb>(x, qw, qb, l, xw);
}

// Kernel E1: normalize xw by l, then out0[b, h*64+c] = xw_n · wvg[:, h*64+c] + bvg.
template<class LDT>
__device__ void kE1_body(const float* xw_ws, const float* l_ws,
    const void* wvg, const void* bvg, float* out0_ws) {
  int h = blockIdx.x, b = blockIdx.y, t = threadIdx.x;
  __shared__ float xws[DM];
  __shared__ float red[4][64];
  float inv = 1.f / l_ws[b*NH + h];
  for (int i = 0; i < 3; ++i) {
    int j = t + 256*i;
    xws[j] = xw_ws[((size_t)b*NH + h)*DM + j] * inv;
  }
  __syncthreads();
  int ci = t & 63, g = t >> 6;
  float acc = 0.f;
  for (int j = g*192; j < g*192 + 192; ++j)
    acc += xws[j] * LDT::s(wvg, (size_t)j*DM + h*64 + ci);
  red[g][ci] = acc;
  __syncthreads();
  if (t < 64) {
    float r = red[0][t] + red[1][t] + red[2][t] + red[3][t] + LDT::s(bvg, h*64 + t);
    out0_ws[b*DM + h*64 + t] = r;
  }
}
__global__ __launch_bounds__(256) void kE1(const float* xw, const float* l,
    const void* wvg, const void* bvg, float* out0, const int* flag) {
  if (*flag) kE1_body<LDf>(xw, l, wvg, bvg, out0);
  else       kE1_body<LDb>(xw, l, wvg, bvg, out0);
}

// Generic matvec: out[b][tile*64+c] = act( in[b][:] · W[:,c] + bias[c] )
template<class LDT>
__device__ void kMV_body(const float* in_ws, const void* Wt, const void* bias,
    float* out_f, void* out_t, int C, int act) {
  int tile = blockIdx.x, b = blockIdx.y, t = threadIdx.x;
  __shared__ float inl[DM];
  __shared__ float red[4][64];
  for (int i = t; i < DM; i += 256) inl[i] = in_ws[b*DM + i];
  __syncthreads();
  int ci = t & 63, g = t >> 6;
  int c = tile*64 + ci;
  float acc = 0.f;
  for (int j = g*192; j < g*192 + 192; ++j)
    acc += inl[j] * LDT::s(Wt, (size_t)j*C + c);
  red[g][ci] = acc;
  __syncthreads();
  if (t < 64) {
    float r = red[0][t] + red[1][t] + red[2][t] + red[3][t] + LDT::s(bias, tile*64 + t);
    if (act) r = tanhf(r);
    size_t oi = (size_t)b*C + tile*64 + t;
    if (out_f) out_f[oi] = r;
    else       LDT::st(out_t, oi, r);
  }
}
__global__ __launch_bounds__(256) void kMV(const float* in_ws, const void* Wt,
    const void* bias, float* out_f, void* out_t, int C, int act, const int* flag) {
  if (*flag) kMV_body<LDf>(in_ws, Wt, bias, out_f, out_t, C, act);
  else       kMV_body<LDb>(in_ws, Wt, bias, out_f, out_t, C, act);
}

extern "C" void kernel_launch(void* const* d_in, const int* in_sizes, int n_in,
                              void* d_out, int out_size, void* d_ws, size_t ws_size,
                              hipStream_t stream) {
  const void* x   = d_in[0];
  const void* wqg = d_in[7];
  const void* bqg = d_in[8];
  const void* wkg = d_in[9];
  const void* bkg = d_in[10];
  const void* wvg = d_in[11];
  const void* bvg = d_in[12];
  const void* wo  = d_in[13];
  const void* bo  = d_in[14];
  const void* wp  = d_in[15];
  const void* bp  = d_in[16];
  const void* wfc = d_in[17];
  const void* bfc = d_in[18];

  float* ws     = (float*)d_ws;
  int*   flag   = (int*)d_ws;      // ws[0]
  float* qw     = ws + 16;         // 18432
  float* qb     = ws + 18448;      // 24
  float* l      = ws + 18472;      // 24
  float* xw     = ws + 18496;      // 18432
  float* out0   = ws + 36928;      // 1536
  float* attn0  = ws + 38464;      // 1536
  float* pooled = ws + 40000;      // 1536  -> total 41536 floats = 166 KB

  kDetect<<<1, 256, 0, stream>>>((const u16*)x, flag);
  kA <<<dim3(NH, BB),     256, 0, stream>>>(x, wqg, bqg, wkg, bkg, qw, qb, l, xw, flag);
  kB <<<dim3(NCHUNK, BB), 256, 0, stream>>>(x, qw, qb, l, xw, flag);
  kE1<<<dim3(NH, BB),     256, 0, stream>>>(xw, l, wvg, bvg, out0, flag);
  kMV<<<dim3(12, BB),     256, 0, stream>>>(out0,  wo,  bo,  attn0,  nullptr, 768,  0, flag);
  kMV<<<dim3(12, BB),     256, 0, stream>>>(attn0, wp,  bp,  pooled, nullptr, 768,  1, flag);
  kMV<<<dim3(8, BB),      256, 0, stream>>>(pooled, wfc, bfc, nullptr, d_out, OUTC, 0, flag);
}

// Round 3
// 199.416 us; speedup vs baseline: 1.1304x; 1.1304x over previous
//
#include <hip/hip_runtime.h>
#include <hip/hip_bf16.h>

#define BB 2
#define SS 4096
#define DM 768
#define NH 12
#define OUTC 512
#define QSCALE 0.125f
#define NCHUNK 128   // s-chunks per batch in kernel B
#define CS 32        // s per chunk
#define JT 32        // j-split blocks for tail matvecs (24 rows each)

__device__ __forceinline__ float wave_sum64(float v) {
#pragma unroll
  for (int o = 32; o > 0; o >>= 1) v += __shfl_xor(v, o, 64);
  return v;
}

// Kernel A: per (h,b,js): qg0 = (x[b,0,:]@wqg+bqg)[h*64:..]*QSCALE (redundant per js);
// fold wkg into qw[b,h,js-slice] and qb[b,h]. Zero l and xw slices (ws is poisoned).
__global__ __launch_bounds__(256) void kA(const float* __restrict__ x,
    const float* __restrict__ wqg, const float* __restrict__ bqg,
    const float* __restrict__ wkg, const float* __restrict__ bkg,
    float* __restrict__ qw_ws, float* __restrict__ qb_ws,
    float* __restrict__ l_ws, float* __restrict__ xw_ws) {
  int h = blockIdx.x, b = blockIdx.y, js = blockIdx.z, t = threadIdx.x;
  __shared__ float x0[DM];
  __shared__ float red[4][64];
  __shared__ float qg0[64];
  for (int i = t; i < DM; i += 256) x0[i] = x[(size_t)b*SS*DM + i];
  for (int i = t; i < 384; i += 256)
    xw_ws[((size_t)b*NH + h)*DM + js*384 + i] = 0.f;
  if (js == 0 && t == 0) l_ws[b*NH + h] = 0.f;
  __syncthreads();
  int d = t & 63, g = t >> 6;
  float p = 0.f;
  for (int j = g*192; j < g*192 + 192; ++j)
    p += x0[j] * wqg[(size_t)j*DM + h*64 + d];
  red[g][d] = p;
  __syncthreads();
  if (t < 64)
    qg0[t] = (red[0][t] + red[1][t] + red[2][t] + red[3][t] + bqg[h*64 + t]) * QSCALE;
  __syncthreads();
  if (js == 0 && t == 0) {
    float qb = 0.f;
    for (int dd = 0; dd < 64; ++dd) qb += qg0[dd] * bkg[h*64 + dd];
    qb_ws[b*NH + h] = qb;
  }
  const float4* qg4 = (const float4*)qg0;
  for (int jj = t; jj < 384; jj += 256) {
    int j = js*384 + jj;
    const float4* wr = (const float4*)(wkg + (size_t)j*DM + h*64);
    float acc = 0.f;
#pragma unroll
    for (int q = 0; q < 16; ++q) {
      float4 wv = wr[q], qv = qg4[q];
      acc += wv.x*qv.x + wv.y*qv.y + wv.z*qv.z + wv.w*qv.w;
    }
    qw_ws[((size_t)b*NH + h)*DM + j] = acc;
  }
}

// Kernel B: fused scores + exp + l accumulation + weighted x row-sum (atomic).
// Grid (NCHUNK, BB). Phase1: wave w covers rows w*8..w*8+7 in 2 batches of 4.
__global__ __launch_bounds__(256) void kB(const float* __restrict__ x,
    const float* __restrict__ qw_ws, const float* __restrict__ qb_ws,
    float* __restrict__ l_ws, float* __restrict__ xw_ws) {
  int chunk = blockIdx.x, b = blockIdx.y;
  int t = threadIdx.x, lane = t & 63, w = t >> 6;
  __shared__ alignas(16) float qw[NH*DM];   // 36 KB
  __shared__ float qb[NH];
  __shared__ alignas(16) float pl[CS*NH];   // 1.5 KB
  for (int i = t; i < NH*DM; i += 256) qw[i] = qw_ws[(size_t)b*NH*DM + i];
  if (t < NH) qb[t] = qb_ws[b*NH + t];
  __syncthreads();
  const size_t xbase = ((size_t)b*SS + chunk*CS) * DM;
  const float4* x4 = (const float4*)(x + xbase);
  const float4* qw4 = (const float4*)qw;
  float lacc = 0.f;

  for (int batch = 0; batch < 2; ++batch) {
    int sl = w*8 + batch*4;
    float acc[4][NH];
#pragma unroll
    for (int si = 0; si < 4; ++si)
#pragma unroll
      for (int hh = 0; hh < NH; ++hh) acc[si][hh] = 0.f;
#pragma unroll
    for (int k = 0; k < 3; ++k) {
      int jq = k*64 + lane;            // float4-quad index in [0,192)
      float4 xf[4];
#pragma unroll
      for (int si = 0; si < 4; ++si)
        xf[si] = x4[(size_t)(sl + si)*192 + jq];
#pragma unroll
      for (int hh = 0; hh < NH; ++hh) {
        float4 qv = qw4[hh*192 + jq];
#pragma unroll
        for (int si = 0; si < 4; ++si)
          acc[si][hh] += xf[si].x*qv.x + xf[si].y*qv.y + xf[si].z*qv.z + xf[si].w*qv.w;
      }
    }
    float preg = 0.f;
#pragma unroll
    for (int si = 0; si < 4; ++si)
#pragma unroll
      for (int hh = 0; hh < NH; ++hh) {
        float r = wave_sum64(acc[si][hh]);
        float pp = __expf(r + qb[hh]);
        if (lane == hh) lacc += pp;
        if (lane == si*NH + hh) preg = pp;
      }
    if (lane < 4*NH) pl[(sl + lane/NH)*NH + (lane % NH)] = preg;
  }
  if (lane < NH) atomicAdd(&l_ws[b*NH + lane], lacc);
  __syncthreads();

  // phase 2: xw[b][h][:] += sum_s p[s,h] * x[s,:] over this chunk
  float a2[NH][3];
#pragma unroll
  for (int hh = 0; hh < NH; ++hh)
#pragma unroll
    for (int i = 0; i < 3; ++i) a2[hh][i] = 0.f;
  for (int s = 0; s < CS; ++s) {
    float4 p0 = *(const float4*)(&pl[s*NH + 0]);
    float4 p1 = *(const float4*)(&pl[s*NH + 4]);
    float4 p2 = *(const float4*)(&pl[s*NH + 8]);
    float pv[NH] = {p0.x,p0.y,p0.z,p0.w, p1.x,p1.y,p1.z,p1.w, p2.x,p2.y,p2.z,p2.w};
    float xv[3];
#pragma unroll
    for (int i = 0; i < 3; ++i)
      xv[i] = x[xbase + (size_t)s*DM + t + 256*i];
#pragma unroll
    for (int hh = 0; hh < NH; ++hh)
#pragma unroll
      for (int i = 0; i < 3; ++i) a2[hh][i] += pv[hh]*xv[i];
  }
#pragma unroll
  for (int hh = 0; hh < NH; ++hh)
#pragma unroll
    for (int i = 0; i < 3; ++i)
      atomicAdd(&xw_ws[((size_t)b*NH + hh)*DM + t + 256*i], a2[hh][i]);
}

// Kernel E1: normalize xw by l, then out0[b, h*64+c] = xw_n · wvg[:, h*64+c] + bvg.
// Also zeroes attnraw+pooledraw (3072 floats, contiguous at zbuf).
__global__ __launch_bounds__(256) void kE1(const float* __restrict__ xw_ws,
    const float* __restrict__ l_ws, const float* __restrict__ wvg,
    const float* __restrict__ bvg, float* __restrict__ out0_ws,
    float* __restrict__ zbuf) {
  int h = blockIdx.x, b = blockIdx.y, t = threadIdx.x;
  __shared__ float xws[DM];
  __shared__ float red[4][64];
  int bid = b*NH + h;
  if (t < 128) zbuf[bid*128 + t] = 0.f;
  float inv = 1.f / l_ws[b*NH + h];
  for (int i = 0; i < 3; ++i) {
    int j = t + 256*i;
    xws[j] = xw_ws[((size_t)b*NH + h)*DM + j] * inv;
  }
  __syncthreads();
  int ci = t & 63, g = t >> 6;
  float acc = 0.f;
  for (int j = g*192; j < g*192 + 192; ++j)
    acc += xws[j] * wvg[(size_t)j*DM + h*64 + ci];
  red[g][ci] = acc;
  __syncthreads();
  if (t < 64)
    out0_ws[b*DM + h*64 + t] =
        red[0][t] + red[1][t] + red[2][t] + red[3][t] + bvg[h*64 + t];
}

// Tail matvec (768x768), j-split with atomic accumulation, both batches fused.
// outacc[b][c] += sum_{j in slice} (inraw[b][j] + bias[j]) * W[j][c]
__global__ __launch_bounds__(192) void kT(const float* __restrict__ inraw,
    const float* __restrict__ bias, const float* __restrict__ W,
    float* __restrict__ outacc) {
  int jb = blockIdx.x, t = threadIdx.x;
  __shared__ float xs[2][DM/JT];
  const int JR = DM/JT;  // 24
  int j0 = jb*JR;
  if (t < 2*JR) {
    int bb = t / JR, jj = t % JR;
    float v = inraw[bb*DM + j0 + jj];
    if (bias) v += bias[j0 + jj];
    xs[bb][jj] = v;
  }
  __syncthreads();
  float4 a0 = {0,0,0,0}, a1 = {0,0,0,0};
  const float4* W4 = (const float4*)W;
#pragma unroll 4
  for (int jj = 0; jj < JR; ++jj) {
    float4 wv = W4[(size_t)(j0 + jj)*192 + t];
    float s0 = xs[0][jj], s1 = xs[1][jj];
    a0.x += s0*wv.x; a0.y += s0*wv.y; a0.z += s0*wv.z; a0.w += s0*wv.w;
    a1.x += s1*wv.x; a1.y += s1*wv.y; a1.z += s1*wv.z; a1.w += s1*wv.w;
  }
  int c = t*4;
  atomicAdd(&outacc[c+0], a0.x); atomicAdd(&outacc[c+1], a0.y);
  atomicAdd(&outacc[c+2], a0.z); atomicAdd(&outacc[c+3], a0.w);
  atomicAdd(&outacc[DM+c+0], a1.x); atomicAdd(&outacc[DM+c+1], a1.y);
  atomicAdd(&outacc[DM+c+2], a1.z); atomicAdd(&outacc[DM+c+3], a1.w);
}

// Final: out[b][tile*64+c] = tanh(pooledraw[b]+bp) · wfc[:,c] + bfc[c], complete write.
__global__ __launch_bounds__(256) void kT3(const float* __restrict__ pooledraw,
    const float* __restrict__ bp, const float* __restrict__ wfc,
    const float* __restrict__ bfc, float* __restrict__ out) {
  int tile = blockIdx.x, b = blockIdx.y, t = threadIdx.x;
  __shared__ float pl[DM];
  __shared__ float red[4][64];
  for (int i = t; i < DM; i += 256) pl[i] = tanhf(pooledraw[b*DM + i] + bp[i]);
  __syncthreads();
  int ci = t & 63, g = t >> 6;
  int c = tile*64 + ci;
  float acc = 0.f;
  for (int j = g*192; j < g*192 + 192; ++j)
    acc += pl[j] * wfc[(size_t)j*OUTC + c];
  red[g][ci] = acc;
  __syncthreads();
  if (t < 64)
    out[(size_t)b*OUTC + tile*64 + t] =
        red[0][t] + red[1][t] + red[2][t] + red[3][t] + bfc[tile*64 + t];
}

extern "C" void kernel_launch(void* const* d_in, const int* in_sizes, int n_in,
                              void* d_out, int out_size, void* d_ws, size_t ws_size,
                              hipStream_t stream) {
  const float* x   = (const float*)d_in[0];
  const float* wqg = (const float*)d_in[7];
  const float* bqg = (const float*)d_in[8];
  const float* wkg = (const float*)d_in[9];
  const float* bkg = (const float*)d_in[10];
  const float* wvg = (const float*)d_in[11];
  const float* bvg = (const float*)d_in[12];
  const float* wo  = (const float*)d_in[13];
  const float* bo  = (const float*)d_in[14];
  const float* wp  = (const float*)d_in[15];
  const float* bp  = (const float*)d_in[16];
  const float* wfc = (const float*)d_in[17];
  const float* bfc = (const float*)d_in[18];

  float* ws        = (float*)d_ws;
  float* qw        = ws;             // 18432
  float* qb        = ws + 18432;     // 24
  float* l         = ws + 18456;     // 24
  float* xw        = ws + 18480;     // 18432
  float* out0      = ws + 36912;     // 1536
  float* attnraw   = ws + 38448;     // 1536
  float* pooledraw = ws + 39984;     // 1536  (attnraw..pooledraw contiguous = zbuf)

  kA <<<dim3(NH, BB, 2),  256, 0, stream>>>(x, wqg, bqg, wkg, bkg, qw, qb, l, xw);
  kB <<<dim3(NCHUNK, BB), 256, 0, stream>>>(x, qw, qb, l, xw);
  kE1<<<dim3(NH, BB),     256, 0, stream>>>(xw, l, wvg, bvg, out0, attnraw);
  kT <<<dim3(JT),         192, 0, stream>>>(out0, nullptr, wo, attnraw);
  kT <<<dim3(JT),         192, 0, stream>>>(attnraw, bo, wp, pooledraw);
  kT3<<<dim3(8, BB),      256, 0, stream>>>(pooledraw, bp, wfc, bfc, (float*)d_out);
}